// Round 7
// baseline (302.586 us; speedup 1.0000x reference)
//
#include <hip/hip_runtime.h>

typedef unsigned short u16;
typedef unsigned int   u32;
typedef unsigned long long u64;
typedef __attribute__((ext_vector_type(8))) short bf16x8;
typedef __attribute__((ext_vector_type(4))) float f32x4;

#define NOBS 128
#define NN   1280
#define NH   256
#define NO   80
#define TT   5
#define RR   16          // batch rows per block
#define NTHR 1024        // 16 waves/block, 1 col-tile per wave
#define EPITCH 88        // encb row pitch (u16): 176B rows -> 16B aligned, 2-way-max banks (free)
#define SPITCH 18        // s1b/s2b row pitch (u16): 9 dwords, conflict-free
#define ABUF  5120       // A tile buffer u16 count: (5t*2ks*4q)*16m*8

// ws layout (u16 units), 3-way bf16 split (hi | mid | lo grouped per matrix):
//   W1s [3][20][256][64] @0 ; W2s [3][4][256][64] @983040 ; Wos [3][4][128][64] @1179648
//   gbits [8192 rows][5 t][80] @1277952  (spike bit-planes, 16 bits/u16 word)
#define W1TOT   983040
#define W2S_OFF 983040
#define WOS_OFF 1179648
#define WS_TOTAL 1277952
#define GB_OFF  WS_TOTAL          // gbits offset (u16 units), 3276800 u16

#define PREP_BLOCKS 4992          // WS_TOTAL/256
#define ENC_BLOCKS  640           // 8192*20/256

__device__ __forceinline__ float bf2f(u16 u) {
  union { u32 i; float f; } x; x.i = ((u32)u) << 16; return x.f;
}
__device__ __forceinline__ u16 f2bf(float f) {
  union { float f; u32 i; } x; x.f = f;
  u32 i = x.i + 0x7FFFu + ((x.i >> 16) & 1u);   // RNE
  return (u16)(i >> 16);
}

// 3-way bf16 split: w ~= hi + mid + lo, residual <= 2^-27 |w|.
__device__ __forceinline__ u16 split3(float w, int sel) {
  u16 hi = f2bf(w);
  if (sel == 0) return hi;
  float r1 = __fsub_rn(w, bf2f(hi));        // exact
  u16 mid = f2bf(r1);
  if (sel == 1) return mid;
  float r2 = __fsub_rn(r1, bf2f(mid));      // exact
  return f2bf(r2);
}

// Fused prep: blocks [0,4992) split weights; blocks [4992,5632) run the
// population encoder (one thread per (row, 64-bit K-chunk)).
__global__ __launch_bounds__(256) void prep_kernel(
    const float* __restrict__ W1, const float* __restrict__ W2,
    const float* __restrict__ Wo,
    const float* __restrict__ obs, const float* __restrict__ enc_mean,
    const float* __restrict__ enc_std, u16* __restrict__ ws)
{
  int bid = blockIdx.x;
  if (bid < PREP_BLOCKS) {
    int i = bid * 256 + threadIdx.x;
    if (i < W1TOT) {                          // W1 [256][1280]
      int sel = i / 327680, rem = i - sel * 327680;
      int kc = rem >> 14, r = rem & 16383, j = r >> 6, kk = r & 63;
      ws[i] = split3(W1[j * 1280 + kc * 64 + kk], sel);
    } else if (i < WOS_OFF) {                 // W2 [256][256]
      int i2 = i - W2S_OFF;
      int sel = i2 >> 16, rem = i2 & 65535;
      int kc = rem >> 14, j = (rem >> 6) & 255, kk = rem & 63;
      ws[i] = split3(W2[j * 256 + kc * 64 + kk], sel);
    } else {                                  // Wo [80][256] padded to 128 rows
      int i3 = i - WOS_OFF;
      int sel = i3 >> 15, rem = i3 & 32767;
      int kc = rem >> 13, j = (rem >> 6) & 127, kk = rem & 63;
      float w = (j < NO) ? Wo[j * 256 + kc * 64 + kk] : 0.f;
      ws[i] = split3(w, sel);
    }
    return;
  }
  // ---- encoder ----
  int gid = (bid - PREP_BLOCKS) * 256 + threadIdx.x;   // < 8192*20
  int r = gid / 20, c = gid - (gid / 20) * 20;
  u64 bits[TT] = {0, 0, 0, 0, 0};
  const float* obsrow = obs + r * NOBS;
  for (int e = 0; e < 64; ++e) {
    int k = c * 64 + e;
    int f = k / 10;
    float x  = obsrow[f];
    float m  = enc_mean[k];
    float sd = enc_std[k];
    float d  = __fsub_rn(x, m);
    float arg = __fdiv_rn(__fmul_rn(-0.5f, __fmul_rn(d, d)), __fmul_rn(sd, sd));
    float a = (float)exp((double)arg);   // correctly-rounded f32 exp of f32 arg
    float v = 0.f;
    #pragma unroll
    for (int t = 0; t < TT; ++t) {
      v = __fadd_rn(v, a);
      if (v > 0.999f) { bits[t] |= (1ull << e); v = __fsub_rn(v, 0.999f); }
    }
  }
  u16* gb = ws + GB_OFF + r * 400 + c * 4;   // [row][t][80]
  #pragma unroll
  for (int t = 0; t < TT; ++t)
    *(u64*)(gb + t * 80) = bits[t];          // 8B aligned, little-endian == u16[4]
}

// Expand one 64-bit K-chunk of spike bits into fragment-order bf16 LDS:
// flat = (((t*2+ks)*4+q)*16 + m16)*8 + j  -> wave ds_read_b128 lane-contiguous.
__device__ __forceinline__ void expandA(
    u16* __restrict__ buf, const u16* bits, int bpitch, int kreal, int wv, int lane)
{
  const int jp = lane & 3, m16 = lane >> 2;
  #pragma unroll
  for (int it = 0; it < 3; ++it) {
    int combo = wv + it * 16;
    if (combo < 40) {
      int q = combo & 3, ks = (combo >> 2) & 1, t = combo >> 3;
      int col = ks * 32 + q * 8 + jp * 2;
      int kg = (kreal << 6) + col;
      u16 w = bits[(t * RR + m16) * bpitch + (kg >> 4)];
      int bp = kg & 15;
      u32 val = ((w >> bp) & 1) ? 0x3F80u : 0u;
      if ((w >> (bp + 1)) & 1) val |= 0x3F800000u;
      *(u32*)(&buf[combo * 128 + m16 * 8 + jp * 2]) = val;
    }
  }
}

// Merged-split GEMM, software-pipelined: next chunk's ks0 B-trio prefetched at
// chunk start, ks1 trio mid-chunk (between MFMA halves) -> peak in-flight ~36 regs.
// A double-buffered in LDS, 1 barrier per chunk. sel=0 -> accA ; sel=1,2 -> accB.
__device__ __forceinline__ void gemm_merged(
    u16* __restrict__ bufA0, u16* __restrict__ bufA1,
    const u16* __restrict__ wsbase, int selstride, int nkreal, int nrowB,
    const u16* bits, int bpitch,
    int wv, int lane, bool active,
    f32x4 accA[TT], f32x4 accB[TT])
{
  const int m16 = lane & 15, q = lane >> 4;
  const int rowoff = (wv * 16 + m16) * 64 + q * 8;   // u16 units within chunk

  bf16x8 b0[3], b1[3];
  if (active) {
    const u16* c0 = wsbase + rowoff;
    #pragma unroll
    for (int s = 0; s < 3; ++s) b0[s] = *(const bf16x8*)(c0 + s * selstride);
    #pragma unroll
    for (int s = 0; s < 3; ++s) b1[s] = *(const bf16x8*)(c0 + s * selstride + 32);
  }
  expandA(bufA0, bits, bpitch, 0, wv, lane);
  __syncthreads();

  for (int kr = 0; kr < nkreal; ++kr) {
    u16* cur = (kr & 1) ? bufA1 : bufA0;
    u16* nxt = (kr & 1) ? bufA0 : bufA1;
    const bool more = (kr + 1 < nkreal);
    const u16* nb = wsbase + (kr + 1) * (nrowB * 64) + rowoff;
    bf16x8 n0[3], n1[3];
    if (more && active) {                      // prefetch next ks0 trio NOW
      #pragma unroll
      for (int s = 0; s < 3; ++s) n0[s] = *(const bf16x8*)(nb + s * selstride);
    }
    if (more) expandA(nxt, bits, bpitch, kr + 1, wv, lane);
    if (active) {
      const bf16x8* ab = (const bf16x8*)cur + lane;
      bf16x8 afr[TT];
      #pragma unroll
      for (int t = 0; t < TT; ++t) afr[t] = ab[(t * 2) * 64];
      #pragma unroll
      for (int sel = 0; sel < 3; ++sel) {
        f32x4* acc = sel ? accB : accA;
        #pragma unroll
        for (int t = 0; t < TT; ++t)
          acc[t] = __builtin_amdgcn_mfma_f32_16x16x32_bf16(afr[t], b0[sel], acc[t], 0, 0, 0);
      }
      if (more) {                              // prefetch next ks1 trio mid-chunk
        #pragma unroll
        for (int s = 0; s < 3; ++s) n1[s] = *(const bf16x8*)(nb + s * selstride + 32);
      }
      #pragma unroll
      for (int t = 0; t < TT; ++t) afr[t] = ab[(t * 2 + 1) * 64];
      #pragma unroll
      for (int sel = 0; sel < 3; ++sel) {
        f32x4* acc = sel ? accB : accA;
        #pragma unroll
        for (int t = 0; t < TT; ++t)
          acc[t] = __builtin_amdgcn_mfma_f32_16x16x32_bf16(afr[t], b1[sel], acc[t], 0, 0, 0);
      }
      if (more) {
        #pragma unroll
        for (int s = 0; s < 3; ++s) { b0[s] = n0[s]; b1[s] = n1[s]; }
      }
    }
    __syncthreads();
  }
}

// LIF recurrence over t on accumulated u(t); emit spike bits via ballot
__device__ __forceinline__ void recur_spikes(
    f32x4 acc[TT], const float* __restrict__ bias,
    int lane, int ct0, u16* sbits, int spitch)
{
  const int q = lane >> 4, m16 = lane & 15;
  int j = ct0 * 16 + m16;
  float bj = bias[j];
  #pragma unroll
  for (int rg = 0; rg < 4; ++rg) {
    float c = 0.f, v = 0.f, sprev = 0.f;
    #pragma unroll
    for (int t = 0; t < TT; ++t) {
      float u = acc[t][rg];
      c = __fadd_rn(__fadd_rn(__fmul_rn(c, 0.5f), u), bj);       // (c*0.5 + u) + b
      float vd = __fmul_rn(v, 0.75f);
      v = __fadd_rn((sprev > 0.5f) ? 0.f : vd, c);               // v*0.75*(1-s) + c
      bool sp = v > 0.5f;
      u64 mask = __ballot(sp);
      if (m16 == 0) {
        int row = q * 4 + rg;
        sbits[(t * RR + row) * spitch + ct0] = (u16)(mask >> (q * 16));
      }
      sprev = sp ? 1.f : 0.f;
    }
  }
}

__global__ __launch_bounds__(NTHR, 4) void snn_main(
    const float* __restrict__ b1, const float* __restrict__ b2, const float* __restrict__ bo,
    const float* __restrict__ dec_w, const float* __restrict__ dec_b, const float* __restrict__ log_std,
    const u16* __restrict__ wsW, float* __restrict__ out, int Btot)
{
  __shared__ __align__(16) u16 smem[2 * ABUF + TT * RR * EPITCH];  // 34560 B
  u16* bufA0 = smem;
  u16* bufA1 = smem + ABUF;
  u16* encb  = smem + 2 * ABUF;                 // [5][16][EPITCH]
  u16* s1b   = encb;                            // [5][16][SPITCH] (alias: encb dead after layer1)
  u16* s2b   = encb + TT * RR * SPITCH;
  float* soacc = (float*)(encb + 2 * TT * RR * SPITCH);   // [16][80] f32

  const int tid  = threadIdx.x;
  const int lane = tid & 63;
  const int wv   = tid >> 6;          // 0..15
  const int r0   = blockIdx.x * RR;

  // ---------- copy this block's spike bits (16 rows x 5 t x 80 u16) to LDS ----------
  if (tid < 800) {
    const u16* gb = wsW + GB_OFF + r0 * 400;
    uint4 d = *(const uint4*)(gb + tid * 8);
    int i8 = tid * 8;
    int r = i8 / 400, rem = i8 - r * 400;
    int t = rem / 80, g = rem - t * 80;
    *(uint4*)(&encb[(t * RR + r) * EPITCH + g]) = d;
  }
  __syncthreads();

  f32x4 accA[TT], accB[TT];
  const f32x4 zero4 = {0.f, 0.f, 0.f, 0.f};
#define ZERO_ACC() { _Pragma("unroll") for (int t = 0; t < TT; ++t) { accA[t] = zero4; accB[t] = zero4; } }
#define COMBINE()  { _Pragma("unroll") for (int t = 0; t < TT; ++t) accA[t] += accB[t]; }

  // ---------- layer 1: [80 x 1280] @ [1280 x 256] (3-way split fused) ----------
  ZERO_ACC();
  gemm_merged(bufA0, bufA1, wsW, 327680, 20, 256, encb, EPITCH, wv, lane, true, accA, accB);
  COMBINE();
  recur_spikes(accA, b1, lane, wv, s1b, SPITCH);
  __syncthreads();

  // ---------- layer 2: [80 x 256] @ [256 x 256] ----------
  ZERO_ACC();
  gemm_merged(bufA0, bufA1, wsW + W2S_OFF, 65536, 4, 256, s1b, SPITCH, wv, lane, true, accA, accB);
  COMBINE();
  recur_spikes(accA, b2, lane, wv, s2b, SPITCH);
  __syncthreads();

  // ---------- layer 3: [80 x 256] @ [256 x 80] — waves 0..4 compute ----------
  ZERO_ACC();
  gemm_merged(bufA0, bufA1, wsW + WOS_OFF, 32768, 4, 128, s2b, SPITCH, wv, lane, (wv < 5), accA, accB);
  COMBINE();
  if (wv < 5) {
    const int q = lane >> 4, m16 = lane & 15;
    int j = wv * 16 + m16;
    float bj = bo[j];
    #pragma unroll
    for (int rg = 0; rg < 4; ++rg) {
      float c = 0.f, v = 0.f, sprev = 0.f;
      int cnt = 0;
      #pragma unroll
      for (int t = 0; t < TT; ++t) {
        float u = accA[t][rg];
        c = __fadd_rn(__fadd_rn(__fmul_rn(c, 0.5f), u), bj);
        float vd = __fmul_rn(v, 0.75f);
        v = __fadd_rn((sprev > 0.5f) ? 0.f : vd, c);
        bool sp = v > 0.5f;
        cnt += sp ? 1 : 0;
        sprev = sp ? 1.f : 0.f;
      }
      soacc[(q * 4 + rg) * NO + j] = __fdiv_rn((float)cnt, 5.0f);
    }
  }
  __syncthreads();

  // ---------- decoder: grouped dot + ELU ----------
  if (tid < RR * 8) {
    int r = tid >> 3, a = tid & 7;
    float s = 0.f;
    const float* so = soacc + r * NO + a * 10;
    #pragma unroll
    for (int p = 0; p < 10; ++p)
      s = __fadd_rn(s, __fmul_rn(so[p], dec_w[a * 10 + p]));
    s = __fadd_rn(s, dec_b[a]);
    float mu = (s > 0.f) ? s : expm1f(s);
    out[(r0 + r) * 8 + a] = mu;
  }
  if (blockIdx.x == 0 && tid < 8) {
    out[Btot * 8 + tid] = expf(log_std[tid]);
  }
}

extern "C" void kernel_launch(void* const* d_in, const int* in_sizes, int n_in,
                              void* d_out, int out_size, void* d_ws, size_t ws_size,
                              hipStream_t stream) {
  const float* obs      = (const float*)d_in[0];
  const float* enc_mean = (const float*)d_in[1];
  const float* enc_std  = (const float*)d_in[2];
  const float* W1       = (const float*)d_in[3];
  const float* b1       = (const float*)d_in[4];
  const float* W2       = (const float*)d_in[5];
  const float* b2       = (const float*)d_in[6];
  const float* Wo       = (const float*)d_in[7];
  const float* bo       = (const float*)d_in[8];
  const float* dec_w    = (const float*)d_in[9];
  const float* dec_b    = (const float*)d_in[10];
  const float* log_std  = (const float*)d_in[11];
  u16*   ws  = (u16*)d_ws;
  float* out = (float*)d_out;
  int B = in_sizes[0] / NOBS;   // 8192

  hipLaunchKernelGGL(prep_kernel, dim3(PREP_BLOCKS + ENC_BLOCKS), dim3(256), 0, stream,
                     W1, W2, Wo, obs, enc_mean, enc_std, ws);
  hipLaunchKernelGGL(snn_main, dim3(B / RR), dim3(NTHR), 0, stream,
                     b1, b2, bo, dec_w, dec_b, log_std, ws, out, B);
}

// Round 8
// 243.066 us; speedup vs baseline: 1.2449x; 1.2449x over previous
//
#include <hip/hip_runtime.h>

typedef unsigned short u16;
typedef unsigned int   u32;
typedef unsigned long long u64;
typedef __attribute__((ext_vector_type(8))) short bf16x8;
typedef __attribute__((ext_vector_type(4))) float f32x4;

#define NOBS 128
#define NN   1280
#define NH   256
#define NO   80
#define TT   5
#define RR   16          // batch rows per block
#define NTHR 1024        // 16 waves/block, 1 col-tile per wave
#define BP1  88          // layer1 bits LDS pitch (u16): 176B rows, 16B-aligned, <=2-way banks
#define BP2  20          // layer2/3 bits pitch (u16): 40B rows, conflict-free

// ws layout (u16 units), 3-way bf16 split (hi | mid | lo grouped per matrix):
//   W1s [3][20][256][64] @0 ; W2s [3][4][256][64] @983040 ; Wos [3][4][128][64] @1179648
//   gbits [8192 rows][5 t][80] @1277952  (spike bit-planes, 16 bits/u16 word)
#define W1TOT   983040
#define W2S_OFF 983040
#define WOS_OFF 1179648
#define WS_TOTAL 1277952
#define GB_OFF  WS_TOTAL

#define PREP_BLOCKS 4992          // WS_TOTAL/256
#define ENC_BLOCKS  2560          // 8192*80/256 (one thread per u16 bit-word)

__device__ __forceinline__ float bf2f(u16 u) {
  union { u32 i; float f; } x; x.i = ((u32)u) << 16; return x.f;
}
__device__ __forceinline__ u16 f2bf(float f) {
  union { float f; u32 i; } x; x.f = f;
  u32 i = x.i + 0x7FFFu + ((x.i >> 16) & 1u);   // RNE
  return (u16)(i >> 16);
}

// 3-way bf16 split: w ~= hi + mid + lo, residual <= 2^-27 |w|.
__device__ __forceinline__ u16 split3(float w, int sel) {
  u16 hi = f2bf(w);
  if (sel == 0) return hi;
  float r1 = __fsub_rn(w, bf2f(hi));        // exact
  u16 mid = f2bf(r1);
  if (sel == 1) return mid;
  float r2 = __fsub_rn(r1, bf2f(mid));      // exact
  return f2bf(r2);
}

// Inline near-correctly-rounded f32 exp via f64 degree-11 Taylor (rel err ~7e-15,
// CR except ~1e-7 of halfway cases; spike-relevant zone arg in (-1.62, 0]).
__device__ __forceinline__ float exp_cr(float arg) {
  double xa = (double)arg;
  double nd = __builtin_rint(xa * 1.4426950408889634074);
  double r  = fma(nd, -6.93147180369123816490e-01, xa);   // ln2_hi (exact for |n|<2^20)
  r         = fma(nd, -1.90821492927058770002e-10, r);    // ln2_lo
  double p = 2.50521083854417187751e-08;                  // 1/11!
  p = fma(p, r, 2.75573192239858906526e-07);              // 1/10!
  p = fma(p, r, 2.75573192239858906526e-06);              // 1/9!
  p = fma(p, r, 2.48015873015873015873e-05);              // 1/8!
  p = fma(p, r, 1.98412698412698412698e-04);              // 1/7!
  p = fma(p, r, 1.38888888888888888889e-03);              // 1/6!
  p = fma(p, r, 8.33333333333333333333e-03);              // 1/5!
  p = fma(p, r, 4.16666666666666666667e-02);              // 1/4!
  p = fma(p, r, 1.66666666666666666667e-01);              // 1/3!
  p = fma(p, r, 0.5);
  p = fma(p, r, 1.0);
  p = fma(p, r, 1.0);
  int n = (int)nd;
  union { u64 u; double d; } s;
  s.u = ((u64)(u32)(n + 1023)) << 52;                     // garbage if n<-150 (discarded)
  return (n < -150) ? 0.f : (float)(s.d * p);
}

// Fused prep: blocks [0,4992) split weights; blocks [4992,7552) run the encoder
// (one thread per (row, u16 bit-word) = 16 receptive fields each).
__global__ __launch_bounds__(256) void prep_kernel(
    const float* __restrict__ W1, const float* __restrict__ W2,
    const float* __restrict__ Wo,
    const float* __restrict__ obs, const float* __restrict__ enc_mean,
    const float* __restrict__ enc_std, u16* __restrict__ ws)
{
  int bid = blockIdx.x;
  if (bid < PREP_BLOCKS) {
    int i = bid * 256 + threadIdx.x;
    if (i < W1TOT) {                          // W1 [256][1280]
      int sel = i / 327680, rem = i - sel * 327680;
      int kc = rem >> 14, r = rem & 16383, j = r >> 6, kk = r & 63;
      ws[i] = split3(W1[j * 1280 + kc * 64 + kk], sel);
    } else if (i < WOS_OFF) {                 // W2 [256][256]
      int i2 = i - W2S_OFF;
      int sel = i2 >> 16, rem = i2 & 65535;
      int kc = rem >> 14, j = (rem >> 6) & 255, kk = rem & 63;
      ws[i] = split3(W2[j * 256 + kc * 64 + kk], sel);
    } else {                                  // Wo [80][256] padded to 128 rows
      int i3 = i - WOS_OFF;
      int sel = i3 >> 15, rem = i3 & 32767;
      int kc = rem >> 13, j = (rem >> 6) & 127, kk = rem & 63;
      float w = (j < NO) ? Wo[j * 256 + kc * 64 + kk] : 0.f;
      ws[i] = split3(w, sel);
    }
    return;
  }
  // ---- encoder ----
  int gid = (bid - PREP_BLOCKS) * 256 + threadIdx.x;   // < 8192*80
  int r = gid / 80, w = gid - (gid / 80) * 80;
  const float* obsrow = obs + r * NOBS;
  u32 wbits[TT] = {0, 0, 0, 0, 0};
  #pragma unroll
  for (int e = 0; e < 16; ++e) {
    int k = w * 16 + e;
    int f = k / 10;
    float x  = obsrow[f];
    float m  = enc_mean[k];
    float sd = enc_std[k];
    float d  = __fsub_rn(x, m);
    float arg = __fdiv_rn(__fmul_rn(-0.5f, __fmul_rn(d, d)), __fmul_rn(sd, sd));
    float a = exp_cr(arg);
    float v = 0.f;
    #pragma unroll
    for (int t = 0; t < TT; ++t) {
      v = __fadd_rn(v, a);
      if (v > 0.999f) { wbits[t] |= (1u << e); v = __fsub_rn(v, 0.999f); }
    }
  }
  u16* gb = ws + GB_OFF + r * 400 + w;       // [row][t][80]
  #pragma unroll
  for (int t = 0; t < TT; ++t) gb[t * 80] = (u16)wbits[t];
}

// Expand 8 spike bits (one byte) -> bf16x8 A-fragment in registers
__device__ __forceinline__ void build_afr(bf16x8 afr[TT], const u64 bw[TT], int sh) {
  #pragma unroll
  for (int t = 0; t < TT; ++t) {
    u32 b = (u32)(bw[t] >> sh) & 0xFFu;
    union { u32 u[4]; bf16x8 v; } x;
    x.u[0] = ((b &   1u) ? 0x3F80u : 0u) | ((b &   2u) ? 0x3F800000u : 0u);
    x.u[1] = ((b &   4u) ? 0x3F80u : 0u) | ((b &   8u) ? 0x3F800000u : 0u);
    x.u[2] = ((b &  16u) ? 0x3F80u : 0u) | ((b &  32u) ? 0x3F800000u : 0u);
    x.u[3] = ((b &  64u) ? 0x3F80u : 0u) | ((b & 128u) ? 0x3F800000u : 0u);
    afr[t] = x.v;
  }
}

// Barrier-free merged-split GEMM: A expanded from LDS bit-planes in registers,
// B trios pipelined from global/L2 (b1 issued chunk-start, b0-next mid-chunk).
// sel=0 (hi) -> accA ; sel=1,2 (mid,lo) -> accB. One 16-col tile per wave.
__device__ __forceinline__ void gemm_reg(
    const u16* __restrict__ lbits, int bpitch,
    const u16* __restrict__ wsbase, int selstride, int nkc, int nrowB,
    int wv, int lane, f32x4 accA[TT], f32x4 accB[TT])
{
  const int m16 = lane & 15, q = lane >> 4;
  const int rowoff = (wv * 16 + m16) * 64 + q * 8;   // u16 units within chunk
  const int sh0 = (q >> 1) * 16 + (q & 1) * 8;       // ks=0 byte shift; ks=1: +32
  const int rowB64 = nrowB * 64;

  bf16x8 b0[3];
  {
    const u16* c0 = wsbase + rowoff;
    #pragma unroll
    for (int s = 0; s < 3; ++s) b0[s] = *(const bf16x8*)(c0 + s * selstride);
  }
  for (int kc = 0; kc < nkc; ++kc) {
    const u16* cb = wsbase + kc * rowB64 + rowoff;
    bf16x8 b1[3];
    #pragma unroll
    for (int s = 0; s < 3; ++s) b1[s] = *(const bf16x8*)(cb + s * selstride + 32);
    u64 bw[TT];
    #pragma unroll
    for (int t = 0; t < TT; ++t)
      bw[t] = *(const u64*)(lbits + (t * RR + m16) * bpitch + kc * 4);
    bf16x8 afr[TT];
    build_afr(afr, bw, sh0);
    #pragma unroll
    for (int sel = 0; sel < 3; ++sel) {
      f32x4* acc = sel ? accB : accA;
      #pragma unroll
      for (int t = 0; t < TT; ++t)
        acc[t] = __builtin_amdgcn_mfma_f32_16x16x32_bf16(afr[t], b0[sel], acc[t], 0, 0, 0);
    }
    bf16x8 n0[3];
    const bool more = (kc + 1 < nkc);
    if (more) {
      const u16* nb = cb + rowB64;
      #pragma unroll
      for (int s = 0; s < 3; ++s) n0[s] = *(const bf16x8*)(nb + s * selstride);
    }
    build_afr(afr, bw, sh0 + 32);
    #pragma unroll
    for (int sel = 0; sel < 3; ++sel) {
      f32x4* acc = sel ? accB : accA;
      #pragma unroll
      for (int t = 0; t < TT; ++t)
        acc[t] = __builtin_amdgcn_mfma_f32_16x16x32_bf16(afr[t], b1[sel], acc[t], 0, 0, 0);
    }
    if (more) {
      #pragma unroll
      for (int s = 0; s < 3; ++s) b0[s] = n0[s];
    }
  }
}

// LIF recurrence over t on accumulated u(t); emit spike bits via ballot
__device__ __forceinline__ void recur_spikes(
    f32x4 acc[TT], const float* __restrict__ bias,
    int lane, int ct0, u16* sbits, int spitch)
{
  const int q = lane >> 4, m16 = lane & 15;
  int j = ct0 * 16 + m16;
  float bj = bias[j];
  #pragma unroll
  for (int rg = 0; rg < 4; ++rg) {
    float c = 0.f, v = 0.f, sprev = 0.f;
    #pragma unroll
    for (int t = 0; t < TT; ++t) {
      float u = acc[t][rg];
      c = __fadd_rn(__fadd_rn(__fmul_rn(c, 0.5f), u), bj);       // (c*0.5 + u) + b
      float vd = __fmul_rn(v, 0.75f);
      v = __fadd_rn((sprev > 0.5f) ? 0.f : vd, c);               // v*0.75*(1-s) + c
      bool sp = v > 0.5f;
      u64 mask = __ballot(sp);
      if (m16 == 0) {
        int row = q * 4 + rg;
        sbits[(t * RR + row) * spitch + ct0] = (u16)(mask >> (q * 16));
      }
      sprev = sp ? 1.f : 0.f;
    }
  }
}

__global__ __launch_bounds__(NTHR, 4) void snn_main(
    const float* __restrict__ b1, const float* __restrict__ b2, const float* __restrict__ bo,
    const float* __restrict__ dec_w, const float* __restrict__ dec_b, const float* __restrict__ log_std,
    const u16* __restrict__ wsW, float* __restrict__ out, int Btot)
{
  __shared__ __align__(16) u16 smem[80 * BP1 + 2 * 80 * BP2 + 2560];  // 25600 B
  u16* encb = smem;                                  // [5*16][BP1]
  u16* s1b  = smem + 80 * BP1;                       // [5*16][BP2]
  u16* s2b  = s1b + 80 * BP2;
  float* soacc = (float*)(s2b + 80 * BP2);           // [16][80] f32

  const int tid  = threadIdx.x;
  const int lane = tid & 63;
  const int wv   = tid >> 6;          // 0..15
  const int r0   = blockIdx.x * RR;

  // ---------- copy this block's spike bit-planes (16 rows x 5 t x 80 u16) to LDS ----------
  if (tid < 800) {
    const u16* gb = wsW + GB_OFF + r0 * 400;
    uint4 d = *(const uint4*)(gb + tid * 8);
    int i8 = tid * 8;
    int r = i8 / 400, rem = i8 - r * 400;
    int t = rem / 80, g = rem - t * 80;
    *(uint4*)(&encb[(t * RR + r) * BP1 + g]) = d;
  }
  __syncthreads();

  f32x4 accA[TT], accB[TT];
  const f32x4 zero4 = {0.f, 0.f, 0.f, 0.f};
#define ZERO_ACC() { _Pragma("unroll") for (int t = 0; t < TT; ++t) { accA[t] = zero4; accB[t] = zero4; } }
#define COMBINE()  { _Pragma("unroll") for (int t = 0; t < TT; ++t) accA[t] += accB[t]; }

  // ---------- layer 1: [80 x 1280] @ [1280 x 256] (3-way split fused) ----------
  ZERO_ACC();
  gemm_reg(encb, BP1, wsW, 327680, 20, 256, wv, lane, accA, accB);
  COMBINE();
  recur_spikes(accA, b1, lane, wv, s1b, BP2);
  __syncthreads();

  // ---------- layer 2: [80 x 256] @ [256 x 256] ----------
  ZERO_ACC();
  gemm_reg(s1b, BP2, wsW + W2S_OFF, 65536, 4, 256, wv, lane, accA, accB);
  COMBINE();
  recur_spikes(accA, b2, lane, wv, s2b, BP2);
  __syncthreads();

  // ---------- layer 3: [80 x 256] @ [256 x 80] — waves 0..4 compute ----------
  if (wv < 5) {
    ZERO_ACC();
    gemm_reg(s2b, BP2, wsW + WOS_OFF, 32768, 4, 128, wv, lane, accA, accB);
    COMBINE();
    const int q = lane >> 4, m16 = lane & 15;
    int j = wv * 16 + m16;
    float bj = bo[j];
    #pragma unroll
    for (int rg = 0; rg < 4; ++rg) {
      float c = 0.f, v = 0.f, sprev = 0.f;
      int cnt = 0;
      #pragma unroll
      for (int t = 0; t < TT; ++t) {
        float u = accA[t][rg];
        c = __fadd_rn(__fadd_rn(__fmul_rn(c, 0.5f), u), bj);
        float vd = __fmul_rn(v, 0.75f);
        v = __fadd_rn((sprev > 0.5f) ? 0.f : vd, c);
        bool sp = v > 0.5f;
        cnt += sp ? 1 : 0;
        sprev = sp ? 1.f : 0.f;
      }
      soacc[(q * 4 + rg) * NO + j] = __fdiv_rn((float)cnt, 5.0f);
    }
  }
  __syncthreads();

  // ---------- decoder: grouped dot + ELU ----------
  if (tid < RR * 8) {
    int r = tid >> 3, a = tid & 7;
    float s = 0.f;
    const float* so = soacc + r * NO + a * 10;
    #pragma unroll
    for (int p = 0; p < 10; ++p)
      s = __fadd_rn(s, __fmul_rn(so[p], dec_w[a * 10 + p]));
    s = __fadd_rn(s, dec_b[a]);
    float mu = (s > 0.f) ? s : expm1f(s);
    out[(r0 + r) * 8 + a] = mu;
  }
  if (blockIdx.x == 0 && tid < 8) {
    out[Btot * 8 + tid] = expf(log_std[tid]);
  }
}

extern "C" void kernel_launch(void* const* d_in, const int* in_sizes, int n_in,
                              void* d_out, int out_size, void* d_ws, size_t ws_size,
                              hipStream_t stream) {
  const float* obs      = (const float*)d_in[0];
  const float* enc_mean = (const float*)d_in[1];
  const float* enc_std  = (const float*)d_in[2];
  const float* W1       = (const float*)d_in[3];
  const float* b1       = (const float*)d_in[4];
  const float* W2       = (const float*)d_in[5];
  const float* b2       = (const float*)d_in[6];
  const float* Wo       = (const float*)d_in[7];
  const float* bo       = (const float*)d_in[8];
  const float* dec_w    = (const float*)d_in[9];
  const float* dec_b    = (const float*)d_in[10];
  const float* log_std  = (const float*)d_in[11];
  u16*   ws  = (u16*)d_ws;
  float* out = (float*)d_out;
  int B = in_sizes[0] / NOBS;   // 8192

  hipLaunchKernelGGL(prep_kernel, dim3(PREP_BLOCKS + ENC_BLOCKS), dim3(256), 0, stream,
                     W1, W2, Wo, obs, enc_mean, enc_std, ws);
  hipLaunchKernelGGL(snn_main, dim3(B / RR), dim3(NTHR), 0, stream,
                     b1, b2, bo, dec_w, dec_b, log_std, ws, out, B);
}

// Round 9
// 239.903 us; speedup vs baseline: 1.2613x; 1.0132x over previous
//
#include <hip/hip_runtime.h>

typedef unsigned short u16;
typedef unsigned int   u32;
typedef unsigned long long u64;
typedef __attribute__((ext_vector_type(8))) short bf16x8;
typedef __attribute__((ext_vector_type(4))) float f32x4;

#define NOBS 128
#define NN   1280
#define NH   256
#define NO   80
#define TT   5
#define RR   16          // batch rows per block
#define NTHR 512         // 8 waves/block, 2 col-tiles per wave
#define BP1  88          // layer1 bits LDS pitch (u16)
#define BP2  20          // layer2/3 bits pitch (u16)

// ws layout (u16 units), 3-way bf16 split (hi | mid | lo grouped per matrix):
//   W1s [3][20][256][64] @0 ; W2s [3][4][256][64] @983040 ; Wos [3][4][128][64] @1179648
//   gbits [8192 rows][5 t][80] @1277952  (spike bit-planes, 16 bits/u16 word)
#define W1TOT   983040
#define W2S_OFF 983040
#define WOS_OFF 1179648
#define WS_TOTAL 1277952
#define GB_OFF  WS_TOTAL

#define PREP_BLOCKS 4992          // WS_TOTAL/256
#define ENC_BLOCKS  2560          // 8192*80/256 (one thread per u16 bit-word)

__device__ __forceinline__ float bf2f(u16 u) {
  union { u32 i; float f; } x; x.i = ((u32)u) << 16; return x.f;
}
__device__ __forceinline__ u16 f2bf(float f) {
  union { float f; u32 i; } x; x.f = f;
  u32 i = x.i + 0x7FFFu + ((x.i >> 16) & 1u);   // RNE
  return (u16)(i >> 16);
}

// 3-way bf16 split: w ~= hi + mid + lo, residual <= 2^-27 |w|.
__device__ __forceinline__ u16 split3(float w, int sel) {
  u16 hi = f2bf(w);
  if (sel == 0) return hi;
  float r1 = __fsub_rn(w, bf2f(hi));        // exact
  u16 mid = f2bf(r1);
  if (sel == 1) return mid;
  float r2 = __fsub_rn(r1, bf2f(mid));      // exact
  return f2bf(r2);
}

// Inline near-correctly-rounded f32 exp via f64 degree-11 Taylor.
__device__ __forceinline__ float exp_cr(float arg) {
  double xa = (double)arg;
  double nd = __builtin_rint(xa * 1.4426950408889634074);
  double r  = fma(nd, -6.93147180369123816490e-01, xa);
  r         = fma(nd, -1.90821492927058770002e-10, r);
  double p = 2.50521083854417187751e-08;
  p = fma(p, r, 2.75573192239858906526e-07);
  p = fma(p, r, 2.75573192239858906526e-06);
  p = fma(p, r, 2.48015873015873015873e-05);
  p = fma(p, r, 1.98412698412698412698e-04);
  p = fma(p, r, 1.38888888888888888889e-03);
  p = fma(p, r, 8.33333333333333333333e-03);
  p = fma(p, r, 4.16666666666666666667e-02);
  p = fma(p, r, 1.66666666666666666667e-01);
  p = fma(p, r, 0.5);
  p = fma(p, r, 1.0);
  p = fma(p, r, 1.0);
  int n = (int)nd;
  union { u64 u; double d; } s;
  s.u = ((u64)(u32)(n + 1023)) << 52;
  return (n < -150) ? 0.f : (float)(s.d * p);
}

// Fused prep: blocks [0,4992) split weights; blocks [4992,7552) run the encoder.
__global__ __launch_bounds__(256) void prep_kernel(
    const float* __restrict__ W1, const float* __restrict__ W2,
    const float* __restrict__ Wo,
    const float* __restrict__ obs, const float* __restrict__ enc_mean,
    const float* __restrict__ enc_std, u16* __restrict__ ws)
{
  int bid = blockIdx.x;
  if (bid < PREP_BLOCKS) {
    int i = bid * 256 + threadIdx.x;
    if (i < W1TOT) {                          // W1 [256][1280]
      int sel = i / 327680, rem = i - sel * 327680;
      int kc = rem >> 14, r = rem & 16383, j = r >> 6, kk = r & 63;
      ws[i] = split3(W1[j * 1280 + kc * 64 + kk], sel);
    } else if (i < WOS_OFF) {                 // W2 [256][256]
      int i2 = i - W2S_OFF;
      int sel = i2 >> 16, rem = i2 & 65535;
      int kc = rem >> 14, j = (rem >> 6) & 255, kk = rem & 63;
      ws[i] = split3(W2[j * 256 + kc * 64 + kk], sel);
    } else {                                  // Wo [80][256] padded to 128 rows
      int i3 = i - WOS_OFF;
      int sel = i3 >> 15, rem = i3 & 32767;
      int kc = rem >> 13, j = (rem >> 6) & 127, kk = rem & 63;
      float w = (j < NO) ? Wo[j * 256 + kc * 64 + kk] : 0.f;
      ws[i] = split3(w, sel);
    }
    return;
  }
  // ---- encoder ----
  int gid = (bid - PREP_BLOCKS) * 256 + threadIdx.x;   // < 8192*80
  int r = gid / 80, w = gid - (gid / 80) * 80;
  const float* obsrow = obs + r * NOBS;
  u32 wbits[TT] = {0, 0, 0, 0, 0};
  #pragma unroll
  for (int e = 0; e < 16; ++e) {
    int k = w * 16 + e;
    int f = k / 10;
    float x  = obsrow[f];
    float m  = enc_mean[k];
    float sd = enc_std[k];
    float d  = __fsub_rn(x, m);
    float arg = __fdiv_rn(__fmul_rn(-0.5f, __fmul_rn(d, d)), __fmul_rn(sd, sd));
    float a = exp_cr(arg);
    float v = 0.f;
    #pragma unroll
    for (int t = 0; t < TT; ++t) {
      v = __fadd_rn(v, a);
      if (v > 0.999f) { wbits[t] |= (1u << e); v = __fsub_rn(v, 0.999f); }
    }
  }
  u16* gb = ws + GB_OFF + r * 400 + w;       // [row][t][80]
  #pragma unroll
  for (int t = 0; t < TT; ++t) gb[t * 80] = (u16)wbits[t];
}

// Expand 8 spike bits (one byte) -> bf16x8 A-fragment; mul-spread, 4 VALU/u32.
__device__ __forceinline__ void build_afr(bf16x8 afr[TT], const u64 bw[TT], int sh) {
  #pragma unroll
  for (int t = 0; t < TT; ++t) {
    u32 b = (u32)(bw[t] >> sh) & 0xFFu;
    union { u32 u[4]; bf16x8 v; } x;
    #pragma unroll
    for (int i = 0; i < 4; ++i) {
      u32 two = (b >> (2 * i)) & 3u;
      x.u[i] = ((two * 0x8001u) & 0x00010001u) * 0x3F80u;
    }
    afr[t] = x.v;
  }
}

// Barrier-free merged-split GEMM, 2 col-tiles/wave, single merged accumulator
// (per-chunk chain order: hi,mid,lo @ks0 then hi,mid,lo @ks1). B pairs prefetched
// one sel-group ahead; bits words prefetched one chunk ahead.
__device__ __forceinline__ void gemm2(
    const u16* __restrict__ lbits, int bpitch,
    const u16* __restrict__ wsbase, int selstride, int nkc, int nrowB,
    int wv, int lane, f32x4 acc[2][TT])
{
  const int m16 = lane & 15, q = lane >> 4;
  const int sh0 = q * 8;
  const int rowB64 = nrowB * 64;
  const int ro0 = ((wv * 2) * 16 + m16) * 64 + q * 8;
  const int ro1 = ((wv * 2 + 1) * 16 + m16) * 64 + q * 8;

  bf16x8 bnx0 = *(const bf16x8*)(wsbase + ro0);
  bf16x8 bnx1 = *(const bf16x8*)(wsbase + ro1);
  u64 bw[TT];
  #pragma unroll
  for (int t = 0; t < TT; ++t)
    bw[t] = *(const u64*)(lbits + (t * RR + m16) * bpitch);

  for (int kc = 0; kc < nkc; ++kc) {
    const u16* cb = wsbase + kc * rowB64;
    bf16x8 afr[TT];
    build_afr(afr, bw, sh0);
    #pragma unroll
    for (int sel = 0; sel < 3; ++sel) {
      const bf16x8 b0 = bnx0, b1 = bnx1;
      const u16* nb = (sel < 2) ? (cb + (sel + 1) * selstride) : (cb + 32);
      bnx0 = *(const bf16x8*)(nb + ro0);
      bnx1 = *(const bf16x8*)(nb + ro1);
      #pragma unroll
      for (int t = 0; t < TT; ++t)
        acc[0][t] = __builtin_amdgcn_mfma_f32_16x16x32_bf16(afr[t], b0, acc[0][t], 0, 0, 0);
      #pragma unroll
      for (int t = 0; t < TT; ++t)
        acc[1][t] = __builtin_amdgcn_mfma_f32_16x16x32_bf16(afr[t], b1, acc[1][t], 0, 0, 0);
    }
    build_afr(afr, bw, sh0 + 32);
    if (kc + 1 < nkc) {
      #pragma unroll
      for (int t = 0; t < TT; ++t)
        bw[t] = *(const u64*)(lbits + (t * RR + m16) * bpitch + (kc + 1) * 4);
    }
    #pragma unroll
    for (int sel = 0; sel < 3; ++sel) {
      const bf16x8 b0 = bnx0, b1 = bnx1;
      const u16* nb = (sel < 2) ? (cb + (sel + 1) * selstride + 32) : (cb + rowB64);
      bnx0 = *(const bf16x8*)(nb + ro0);
      bnx1 = *(const bf16x8*)(nb + ro1);
      #pragma unroll
      for (int t = 0; t < TT; ++t)
        acc[0][t] = __builtin_amdgcn_mfma_f32_16x16x32_bf16(afr[t], b0, acc[0][t], 0, 0, 0);
      #pragma unroll
      for (int t = 0; t < TT; ++t)
        acc[1][t] = __builtin_amdgcn_mfma_f32_16x16x32_bf16(afr[t], b1, acc[1][t], 0, 0, 0);
    }
  }
}

// LIF recurrence over t; emit spike bits via ballot. 2 col-tiles per wave.
__device__ __forceinline__ void recur_spikes2(
    f32x4 acc[2][TT], const float* __restrict__ bias,
    int lane, int wv, u16* sbits, int spitch)
{
  const int q = lane >> 4, m16 = lane & 15;
  #pragma unroll
  for (int i = 0; i < 2; ++i) {
    int ct = wv * 2 + i;
    int j = ct * 16 + m16;
    float bj = bias[j];
    #pragma unroll
    for (int rg = 0; rg < 4; ++rg) {
      float c = 0.f, v = 0.f, sprev = 0.f;
      #pragma unroll
      for (int t = 0; t < TT; ++t) {
        float u = acc[i][t][rg];
        c = __fadd_rn(__fadd_rn(__fmul_rn(c, 0.5f), u), bj);       // (c*0.5 + u) + b
        float vd = __fmul_rn(v, 0.75f);
        v = __fadd_rn((sprev > 0.5f) ? 0.f : vd, c);               // v*0.75*(1-s) + c
        bool sp = v > 0.5f;
        u64 mask = __ballot(sp);
        if (m16 == 0) {
          int row = q * 4 + rg;
          sbits[(t * RR + row) * spitch + ct] = (u16)(mask >> (q * 16));
        }
        sprev = sp ? 1.f : 0.f;
      }
    }
  }
}

__global__ __launch_bounds__(NTHR, 4) void snn_main(
    const float* __restrict__ b1, const float* __restrict__ b2, const float* __restrict__ bo,
    const float* __restrict__ dec_w, const float* __restrict__ dec_b, const float* __restrict__ log_std,
    const u16* __restrict__ wsW, float* __restrict__ out, int Btot)
{
  __shared__ __align__(16) u16 smem[80 * BP1 + 2 * 80 * BP2 + 2560];  // 25600 B
  u16* encb = smem;                                  // [5*16][BP1]
  u16* s1b  = smem + 80 * BP1;                       // [5*16][BP2]
  u16* s2b  = s1b + 80 * BP2;
  float* soacc = (float*)(s2b + 80 * BP2);           // [16][80] f32

  const int tid  = threadIdx.x;
  const int lane = tid & 63;
  const int wv   = tid >> 6;          // 0..7
  const int r0   = blockIdx.x * RR;

  // ---------- copy this block's spike bit-planes to LDS ----------
  for (int it = tid; it < 800; it += NTHR) {
    const u16* gb = wsW + GB_OFF + r0 * 400;
    uint4 d = *(const uint4*)(gb + it * 8);
    int i8 = it * 8;
    int r = i8 / 400, rem = i8 - r * 400;
    int t = rem / 80, g = rem - t * 80;
    *(uint4*)(&encb[(t * RR + r) * BP1 + g]) = d;
  }
  __syncthreads();

  f32x4 acc[2][TT];
  const f32x4 zero4 = {0.f, 0.f, 0.f, 0.f};
#define ZERO_ACC() { _Pragma("unroll") for (int i = 0; i < 2; ++i) \
                     _Pragma("unroll") for (int t = 0; t < TT; ++t) acc[i][t] = zero4; }

  // ---------- layer 1: [80 x 1280] @ [1280 x 256] (3-way split fused) ----------
  ZERO_ACC();
  gemm2(encb, BP1, wsW, 327680, 20, 256, wv, lane, acc);
  recur_spikes2(acc, b1, lane, wv, s1b, BP2);
  __syncthreads();

  // ---------- layer 2: [80 x 256] @ [256 x 256] ----------
  ZERO_ACC();
  gemm2(s1b, BP2, wsW + W2S_OFF, 65536, 4, 256, wv, lane, acc);
  recur_spikes2(acc, b2, lane, wv, s2b, BP2);
  __syncthreads();

  // ---------- layer 3: [80 x 256] @ [256 x 80(pad96)] — waves 0..2 ----------
  if (wv < 3) {
    ZERO_ACC();
    gemm2(s2b, BP2, wsW + WOS_OFF, 32768, 4, 128, wv, lane, acc);
    const int q = lane >> 4, m16 = lane & 15;
    #pragma unroll
    for (int i = 0; i < 2; ++i) {
      int j = (wv * 2 + i) * 16 + m16;
      bool valid = j < NO;
      float bj = valid ? bo[j] : 0.f;
      #pragma unroll
      for (int rg = 0; rg < 4; ++rg) {
        float c = 0.f, v = 0.f, sprev = 0.f;
        int cnt = 0;
        #pragma unroll
        for (int t = 0; t < TT; ++t) {
          float u = acc[i][t][rg];
          c = __fadd_rn(__fadd_rn(__fmul_rn(c, 0.5f), u), bj);
          float vd = __fmul_rn(v, 0.75f);
          v = __fadd_rn((sprev > 0.5f) ? 0.f : vd, c);
          bool sp = v > 0.5f;
          cnt += sp ? 1 : 0;
          sprev = sp ? 1.f : 0.f;
        }
        if (valid) soacc[(q * 4 + rg) * NO + j] = __fdiv_rn((float)cnt, 5.0f);
      }
    }
  }
  __syncthreads();

  // ---------- decoder: grouped dot + ELU ----------
  if (tid < RR * 8) {
    int r = tid >> 3, a = tid & 7;
    float s = 0.f;
    const float* so = soacc + r * NO + a * 10;
    #pragma unroll
    for (int p = 0; p < 10; ++p)
      s = __fadd_rn(s, __fmul_rn(so[p], dec_w[a * 10 + p]));
    s = __fadd_rn(s, dec_b[a]);
    float mu = (s > 0.f) ? s : expm1f(s);
    out[(r0 + r) * 8 + a] = mu;
  }
  if (blockIdx.x == 0 && tid < 8) {
    out[Btot * 8 + tid] = expf(log_std[tid]);
  }
}

extern "C" void kernel_launch(void* const* d_in, const int* in_sizes, int n_in,
                              void* d_out, int out_size, void* d_ws, size_t ws_size,
                              hipStream_t stream) {
  const float* obs      = (const float*)d_in[0];
  const float* enc_mean = (const float*)d_in[1];
  const float* enc_std  = (const float*)d_in[2];
  const float* W1       = (const float*)d_in[3];
  const float* b1       = (const float*)d_in[4];
  const float* W2       = (const float*)d_in[5];
  const float* b2       = (const float*)d_in[6];
  const float* Wo       = (const float*)d_in[7];
  const float* bo       = (const float*)d_in[8];
  const float* dec_w    = (const float*)d_in[9];
  const float* dec_b    = (const float*)d_in[10];
  const float* log_std  = (const float*)d_in[11];
  u16*   ws  = (u16*)d_ws;
  float* out = (float*)d_out;
  int B = in_sizes[0] / NOBS;   // 8192

  hipLaunchKernelGGL(prep_kernel, dim3(PREP_BLOCKS + ENC_BLOCKS), dim3(256), 0, stream,
                     W1, W2, Wo, obs, enc_mean, enc_std, ws);
  hipLaunchKernelGGL(snn_main, dim3(B / RR), dim3(NTHR), 0, stream,
                     b1, b2, bo, dec_w, dec_b, log_std, ws, out, B);
}

// Round 10
// 236.924 us; speedup vs baseline: 1.2771x; 1.0126x over previous
//
#include <hip/hip_runtime.h>

typedef unsigned short u16;
typedef unsigned int   u32;
typedef unsigned long long u64;
typedef __attribute__((ext_vector_type(8))) short bf16x8;
typedef __attribute__((ext_vector_type(4))) float f32x4;

#define NOBS 128
#define NN   1280
#define NH   256
#define NO   80
#define TT   5
#define RR   16          // batch rows per block
#define NTHR 512         // 8 waves/block, 2 col-tiles per wave
#define BP1  88          // layer1 bits LDS pitch (u16)
#define BP2  20          // layer2/3 bits pitch (u16)

// ws layout (u16 units), 3-way bf16 split (hi | mid | lo grouped per matrix):
//   W1s [3][20][256][64] @0 ; W2s [3][4][256][64] @983040 ; Wos [3][4][128][64] @1179648
//   gbits [8192 rows][5 t][80] @1277952  (spike bit-planes, 16 bits/u16 word)
#define W1TOT   983040
#define W2S_OFF 983040
#define WOS_OFF 1179648
#define WS_TOTAL 1277952
#define GB_OFF  WS_TOTAL

#define PREP_BLOCKS 4992          // WS_TOTAL/256
#define ENC_BLOCKS  2560          // 8192*80/256 (one thread per u16 bit-word)

__device__ __forceinline__ float bf2f(u16 u) {
  union { u32 i; float f; } x; x.i = ((u32)u) << 16; return x.f;
}
__device__ __forceinline__ u16 f2bf(float f) {
  union { float f; u32 i; } x; x.f = f;
  u32 i = x.i + 0x7FFFu + ((x.i >> 16) & 1u);   // RNE
  return (u16)(i >> 16);
}

// 3-way bf16 split: w ~= hi + mid + lo, residual <= 2^-27 |w|.
__device__ __forceinline__ u16 split3(float w, int sel) {
  u16 hi = f2bf(w);
  if (sel == 0) return hi;
  float r1 = __fsub_rn(w, bf2f(hi));        // exact
  u16 mid = f2bf(r1);
  if (sel == 1) return mid;
  float r2 = __fsub_rn(r1, bf2f(mid));      // exact
  return f2bf(r2);
}

// Inline near-correctly-rounded f32 exp via f64 degree-11 Taylor.
__device__ __forceinline__ float exp_cr(float arg) {
  double xa = (double)arg;
  double nd = __builtin_rint(xa * 1.4426950408889634074);
  double r  = fma(nd, -6.93147180369123816490e-01, xa);
  r         = fma(nd, -1.90821492927058770002e-10, r);
  double p = 2.50521083854417187751e-08;
  p = fma(p, r, 2.75573192239858906526e-07);
  p = fma(p, r, 2.75573192239858906526e-06);
  p = fma(p, r, 2.48015873015873015873e-05);
  p = fma(p, r, 1.98412698412698412698e-04);
  p = fma(p, r, 1.38888888888888888889e-03);
  p = fma(p, r, 8.33333333333333333333e-03);
  p = fma(p, r, 4.16666666666666666667e-02);
  p = fma(p, r, 1.66666666666666666667e-01);
  p = fma(p, r, 0.5);
  p = fma(p, r, 1.0);
  p = fma(p, r, 1.0);
  int n = (int)nd;
  union { u64 u; double d; } s;
  s.u = ((u64)(u32)(n + 1023)) << 52;
  return (n < -150) ? 0.f : (float)(s.d * p);
}

// Fused prep: blocks [0,4992) split weights; blocks [4992,7552) run the encoder.
__global__ __launch_bounds__(256) void prep_kernel(
    const float* __restrict__ W1, const float* __restrict__ W2,
    const float* __restrict__ Wo,
    const float* __restrict__ obs, const float* __restrict__ enc_mean,
    const float* __restrict__ enc_std, u16* __restrict__ ws)
{
  int bid = blockIdx.x;
  if (bid < PREP_BLOCKS) {
    int i = bid * 256 + threadIdx.x;
    if (i < W1TOT) {                          // W1 [256][1280]
      int sel = i / 327680, rem = i - sel * 327680;
      int kc = rem >> 14, r = rem & 16383, j = r >> 6, kk = r & 63;
      ws[i] = split3(W1[j * 1280 + kc * 64 + kk], sel);
    } else if (i < WOS_OFF) {                 // W2 [256][256]
      int i2 = i - W2S_OFF;
      int sel = i2 >> 16, rem = i2 & 65535;
      int kc = rem >> 14, j = (rem >> 6) & 255, kk = rem & 63;
      ws[i] = split3(W2[j * 256 + kc * 64 + kk], sel);
    } else {                                  // Wo [80][256] padded to 128 rows
      int i3 = i - WOS_OFF;
      int sel = i3 >> 15, rem = i3 & 32767;
      int kc = rem >> 13, j = (rem >> 6) & 127, kk = rem & 63;
      float w = (j < NO) ? Wo[j * 256 + kc * 64 + kk] : 0.f;
      ws[i] = split3(w, sel);
    }
    return;
  }
  // ---- encoder ----
  int gid = (bid - PREP_BLOCKS) * 256 + threadIdx.x;   // < 8192*80
  int r = gid / 80, w = gid - (gid / 80) * 80;
  const float* obsrow = obs + r * NOBS;
  u32 wbits[TT] = {0, 0, 0, 0, 0};
  #pragma unroll
  for (int e = 0; e < 16; ++e) {
    int k = w * 16 + e;
    int f = k / 10;
    float x  = obsrow[f];
    float m  = enc_mean[k];
    float sd = enc_std[k];
    float d  = __fsub_rn(x, m);
    float arg = __fdiv_rn(__fmul_rn(-0.5f, __fmul_rn(d, d)), __fmul_rn(sd, sd));
    float a = exp_cr(arg);
    float v = 0.f;
    #pragma unroll
    for (int t = 0; t < TT; ++t) {
      v = __fadd_rn(v, a);
      if (v > 0.999f) { wbits[t] |= (1u << e); v = __fsub_rn(v, 0.999f); }
    }
  }
  u16* gb = ws + GB_OFF + r * 400 + w;       // [row][t][80]
  #pragma unroll
  for (int t = 0; t < TT; ++t) gb[t * 80] = (u16)wbits[t];
}

// Expand 8 spike bits (one byte) -> bf16x8 A-fragment; mul-spread, 4 VALU/u32.
__device__ __forceinline__ void build_afr(bf16x8 afr[TT], const u64 bw[TT], int sh) {
  #pragma unroll
  for (int t = 0; t < TT; ++t) {
    u32 b = (u32)(bw[t] >> sh) & 0xFFu;
    union { u32 u[4]; bf16x8 v; } x;
    #pragma unroll
    for (int i = 0; i < 4; ++i) {
      u32 two = (b >> (2 * i)) & 3u;
      x.u[i] = ((two * 0x8001u) & 0x00010001u) * 0x3F80u;
    }
    afr[t] = x.v;
  }
}

// Barrier-free merged-split GEMM, 2 col-tiles/wave, single merged accumulator.
// Depth-3 B pipeline: groups G = kc*6 + g, g-order (sel0,1,2)@ks0 then @ks1.
// Consuming G waits with 4 newer loads in flight (vmcnt(4)); load for G+3
// issues right after -> load->use distance = 30 MFMAs.
__device__ __forceinline__ void gemm2(
    const u16* __restrict__ lbits, int bpitch,
    const u16* __restrict__ wsbase, int selstride, int nkc, int nrowB,
    int wv, int lane, f32x4 acc[2][TT])
{
  const int m16 = lane & 15, q = lane >> 4;
  const int sh0 = q * 8;
  const int rowB64 = nrowB * 64;
  const int ro0 = ((wv * 2) * 16 + m16) * 64 + q * 8;
  const int ro1 = ro0 + 16 * 64;

  bf16x8 pb0[3], pb1[3];                 // circular queue, slot = G % 3
  #pragma unroll
  for (int g = 0; g < 3; ++g) {          // prologue: G = 0,1,2 (chunk0, ks0)
    const u16* p = wsbase + g * selstride;
    pb0[g] = *(const bf16x8*)(p + ro0);
    pb1[g] = *(const bf16x8*)(p + ro1);
  }
  u64 bw[TT];
  #pragma unroll
  for (int t = 0; t < TT; ++t)
    bw[t] = *(const u64*)(lbits + (t * RR + m16) * bpitch);

  bf16x8 afr[TT];
  for (int kc = 0; kc < nkc; ++kc) {
    const u16* cb = wsbase + kc * rowB64;
    const bool more = (kc + 1 < nkc);
    #pragma unroll
    for (int g = 0; g < 6; ++g) {
      if (g == 0) build_afr(afr, bw, sh0);
      if (g == 3) {
        build_afr(afr, bw, sh0 + 32);
        if (more) {
          #pragma unroll
          for (int t = 0; t < TT; ++t)
            bw[t] = *(const u64*)(lbits + (t * RR + m16) * bpitch + (kc + 1) * 4);
        }
      }
      const int slot = g % 3;
      const bf16x8 b0 = pb0[slot], b1 = pb1[slot];   // waits vmcnt(4)
      // issue loads for G+3: g<3 -> (sel g, ks1) of this chunk; g>=3 -> (sel g-3, ks0) of next
      if (g < 3) {
        const u16* p = cb + g * selstride + 32;
        pb0[slot] = *(const bf16x8*)(p + ro0);
        pb1[slot] = *(const bf16x8*)(p + ro1);
      } else if (more) {
        const u16* p = cb + rowB64 + (g - 3) * selstride;
        pb0[slot] = *(const bf16x8*)(p + ro0);
        pb1[slot] = *(const bf16x8*)(p + ro1);
      }
      #pragma unroll
      for (int t = 0; t < TT; ++t)
        acc[0][t] = __builtin_amdgcn_mfma_f32_16x16x32_bf16(afr[t], b0, acc[0][t], 0, 0, 0);
      #pragma unroll
      for (int t = 0; t < TT; ++t)
        acc[1][t] = __builtin_amdgcn_mfma_f32_16x16x32_bf16(afr[t], b1, acc[1][t], 0, 0, 0);
    }
  }
}

// LIF recurrence over t; emit spike bits via ballot. 2 col-tiles per wave.
__device__ __forceinline__ void recur_spikes2(
    f32x4 acc[2][TT], const float* __restrict__ bias,
    int lane, int wv, u16* sbits, int spitch)
{
  const int q = lane >> 4, m16 = lane & 15;
  #pragma unroll
  for (int i = 0; i < 2; ++i) {
    int ct = wv * 2 + i;
    int j = ct * 16 + m16;
    float bj = bias[j];
    #pragma unroll
    for (int rg = 0; rg < 4; ++rg) {
      float c = 0.f, v = 0.f, sprev = 0.f;
      #pragma unroll
      for (int t = 0; t < TT; ++t) {
        float u = acc[i][t][rg];
        c = __fadd_rn(__fadd_rn(__fmul_rn(c, 0.5f), u), bj);       // (c*0.5 + u) + b
        float vd = __fmul_rn(v, 0.75f);
        v = __fadd_rn((sprev > 0.5f) ? 0.f : vd, c);               // v*0.75*(1-s) + c
        bool sp = v > 0.5f;
        u64 mask = __ballot(sp);
        if (m16 == 0) {
          int row = q * 4 + rg;
          sbits[(t * RR + row) * spitch + ct] = (u16)(mask >> (q * 16));
        }
        sprev = sp ? 1.f : 0.f;
      }
    }
  }
}

__global__ __launch_bounds__(NTHR, 4) void snn_main(
    const float* __restrict__ b1, const float* __restrict__ b2, const float* __restrict__ bo,
    const float* __restrict__ dec_w, const float* __restrict__ dec_b, const float* __restrict__ log_std,
    const u16* __restrict__ wsW, float* __restrict__ out, int Btot)
{
  __shared__ __align__(16) u16 smem[80 * BP1 + 2 * 80 * BP2 + 2560];  // 25600 B
  u16* encb = smem;                                  // [5*16][BP1]
  u16* s1b  = smem + 80 * BP1;                       // [5*16][BP2]
  u16* s2b  = s1b + 80 * BP2;
  float* soacc = (float*)(s2b + 80 * BP2);           // [16][80] f32

  const int tid  = threadIdx.x;
  const int lane = tid & 63;
  const int wv   = tid >> 6;          // 0..7
  const int r0   = blockIdx.x * RR;

  // ---------- copy this block's spike bit-planes to LDS ----------
  for (int it = tid; it < 800; it += NTHR) {
    const u16* gb = wsW + GB_OFF + r0 * 400;
    uint4 d = *(const uint4*)(gb + it * 8);
    int i8 = it * 8;
    int r = i8 / 400, rem = i8 - r * 400;
    int t = rem / 80, g = rem - t * 80;
    *(uint4*)(&encb[(t * RR + r) * BP1 + g]) = d;
  }
  __syncthreads();

  f32x4 acc[2][TT];
  const f32x4 zero4 = {0.f, 0.f, 0.f, 0.f};
#define ZERO_ACC() { _Pragma("unroll") for (int i = 0; i < 2; ++i) \
                     _Pragma("unroll") for (int t = 0; t < TT; ++t) acc[i][t] = zero4; }

  // ---------- layer 1: [80 x 1280] @ [1280 x 256] (3-way split fused) ----------
  ZERO_ACC();
  gemm2(encb, BP1, wsW, 327680, 20, 256, wv, lane, acc);
  recur_spikes2(acc, b1, lane, wv, s1b, BP2);
  __syncthreads();

  // ---------- layer 2: [80 x 256] @ [256 x 256] ----------
  ZERO_ACC();
  gemm2(s1b, BP2, wsW + W2S_OFF, 65536, 4, 256, wv, lane, acc);
  recur_spikes2(acc, b2, lane, wv, s2b, BP2);
  __syncthreads();

  // ---------- layer 3: [80 x 256] @ [256 x 80(pad96)] — waves 0..2 ----------
  if (wv < 3) {
    ZERO_ACC();
    gemm2(s2b, BP2, wsW + WOS_OFF, 32768, 4, 128, wv, lane, acc);
    const int q = lane >> 4, m16 = lane & 15;
    #pragma unroll
    for (int i = 0; i < 2; ++i) {
      int j = (wv * 2 + i) * 16 + m16;
      bool valid = j < NO;
      float bj = valid ? bo[j] : 0.f;
      #pragma unroll
      for (int rg = 0; rg < 4; ++rg) {
        float c = 0.f, v = 0.f, sprev = 0.f;
        int cnt = 0;
        #pragma unroll
        for (int t = 0; t < TT; ++t) {
          float u = acc[i][t][rg];
          c = __fadd_rn(__fadd_rn(__fmul_rn(c, 0.5f), u), bj);
          float vd = __fmul_rn(v, 0.75f);
          v = __fadd_rn((sprev > 0.5f) ? 0.f : vd, c);
          bool sp = v > 0.5f;
          cnt += sp ? 1 : 0;
          sprev = sp ? 1.f : 0.f;
        }
        if (valid) soacc[(q * 4 + rg) * NO + j] = __fdiv_rn((float)cnt, 5.0f);
      }
    }
  }
  __syncthreads();

  // ---------- decoder: grouped dot + ELU ----------
  if (tid < RR * 8) {
    int r = tid >> 3, a = tid & 7;
    float s = 0.f;
    const float* so = soacc + r * NO + a * 10;
    #pragma unroll
    for (int p = 0; p < 10; ++p)
      s = __fadd_rn(s, __fmul_rn(so[p], dec_w[a * 10 + p]));
    s = __fadd_rn(s, dec_b[a]);
    float mu = (s > 0.f) ? s : expm1f(s);
    out[(r0 + r) * 8 + a] = mu;
  }
  if (blockIdx.x == 0 && tid < 8) {
    out[Btot * 8 + tid] = expf(log_std[tid]);
  }
}

extern "C" void kernel_launch(void* const* d_in, const int* in_sizes, int n_in,
                              void* d_out, int out_size, void* d_ws, size_t ws_size,
                              hipStream_t stream) {
  const float* obs      = (const float*)d_in[0];
  const float* enc_mean = (const float*)d_in[1];
  const float* enc_std  = (const float*)d_in[2];
  const float* W1       = (const float*)d_in[3];
  const float* b1       = (const float*)d_in[4];
  const float* W2       = (const float*)d_in[5];
  const float* b2       = (const float*)d_in[6];
  const float* Wo       = (const float*)d_in[7];
  const float* bo       = (const float*)d_in[8];
  const float* dec_w    = (const float*)d_in[9];
  const float* dec_b    = (const float*)d_in[10];
  const float* log_std  = (const float*)d_in[11];
  u16*   ws  = (u16*)d_ws;
  float* out = (float*)d_out;
  int B = in_sizes[0] / NOBS;   // 8192

  hipLaunchKernelGGL(prep_kernel, dim3(PREP_BLOCKS + ENC_BLOCKS), dim3(256), 0, stream,
                     W1, W2, Wo, obs, enc_mean, enc_std, ws);
  hipLaunchKernelGGL(snn_main, dim3(B / RR), dim3(NTHR), 0, stream,
                     b1, b2, bo, dec_w, dec_b, log_std, ws, out, B);
}